// Round 7
// baseline (265.830 us; speedup 1.0000x reference)
//
#include <hip/hip_runtime.h>
#include <hip/hip_bf16.h>

#define NB 64
#define ND 64
#define NQ 2048
#define NS 2048
#define QBLK 512           // q-rows per block (8 waves x 64)
#define SBLK 64
#define QPB 4              // q-blocks per batch = NQ/QBLK
#define NSPLIT 2           // s-range splits per (b,qb)
#define NSS (NS / NSPLIT)  // 1024 s-cols per block
#define NT (NSS / SBLK)    // 16 tiles per block

typedef float f32x4 __attribute__((ext_vector_type(4)));
typedef short bf16x8 __attribute__((ext_vector_type(8)));
typedef int i32x4 __attribute__((ext_vector_type(4)));

// f32 -> bf16 via compiler-visible packed convert (m240: beats inline asm).
__device__ inline i32x4 pack8(const float* f) {
  union { __hip_bfloat162 h2[4]; i32x4 v; } u;
  #pragma unroll
  for (int p = 0; p < 4; ++p)
    u.h2[p] = __float22bfloat162_rn(float2{f[2 * p], f[2 * p + 1]});
  return u.v;
}

// bid = ss*256 + qb*64 + b  (b in low bits -> all blocks of batch b on XCD b%8)
// Block: batch b, 512 q-rows (8 waves x 64), s-cols [ss*1024, +1024).
// A (Q^T) in registers for the whole s-loop. S staged per 64-col tile in LDS
// bf16 [s][d], 16B-slot XOR swizzle. Depth-2 register prefetch (pf ping-pong,
// fully unrolled NT=16 so all indices static), write-early/compute-late,
// ONE barrier per tile. NSPLIT=2 doubles prologue amortization vs R6.
__global__ __launch_bounds__(512, 4) void bmd_main(
    const float* __restrict__ Q, const float* __restrict__ S,
    float* __restrict__ part) {
  const int bid = blockIdx.x;
  const int b  = bid & (NB - 1);
  const int qb = (bid >> 6) & (QPB - 1);
  const int ss = bid >> 8;
  const int q0 = qb * QBLK;
  const int sbase = ss * NSS;
  const int tid = threadIdx.x;
  const int lane = tid & 63;
  const int w = tid >> 6;   // 0..7

  __shared__ char sT[2][SBLK * 128];

  const float* Qb = Q + (size_t)b * ND * NQ;
  const float* Sb = S + (size_t)b * ND * NS;

  // staging: thread -> (d-octet dbq, s-col sl); 512 threads cover 64s x 8 octets
  const int dbq = (tid >> 3) & 7;
  const int sl = (tid & 7) + ((tid >> 6) << 3);   // 0..63
  const int byt = sl * 128 + ((dbq ^ (sl & 7)) << 4);
  const float* stage_src = Sb + (size_t)dbq * 8 * NS + sbase;

  // ---- issue tile-0 and tile-1 loads FIRST (latency hides under Q gather) --
  float f0[8];
  float pf[2][8];   // pf[p] holds the in-flight tile with parity p
  {
    const float* s0 = stage_src + sl;
    #pragma unroll
    for (int e = 0; e < 8; ++e) f0[e] = s0[(size_t)e * NS];
    const float* s1 = stage_src + SBLK + sl;
    #pragma unroll
    for (int e = 0; e < 8; ++e) pf[1][e] = s1[(size_t)e * NS];
  }

  // ---- A fragments: row = lane&15 (q), k = (lane>>4)*8+e (d) ----
  i32x4 afrag[4][2];  // [mf: 16 q-rows each][ks: k-step of 32]
  {
    const int qrow = q0 + w * 64 + (lane & 15);
    const int dbase = (lane >> 4) * 8;
    for (int mf = 0; mf < 4; ++mf)
      for (int ks = 0; ks < 2; ++ks) {
        const int d0 = ks * 32 + dbase;
        float f[8];
        #pragma unroll
        for (int e = 0; e < 8; ++e)
          f[e] = Qb[(size_t)(d0 + e) * NQ + (qrow + mf * 16)];
        afrag[mf][ks] = pack8(f);
      }
  }

  const f32x4 kZero = {0.f, 0.f, 0.f, 0.f};
  f32x4 rmax[4];
  #pragma unroll
  for (int mf = 0; mf < 4; ++mf)
    rmax[mf] = f32x4{-INFINITY, -INFINITY, -INFINITY, -INFINITY};

  // ---- stage tile 0 into LDS, then enter the pipeline ----
  *reinterpret_cast<i32x4*>(sT[0] + byt) = pack8(f0);
  __syncthreads();

  #pragma unroll
  for (int t = 0; t < NT; ++t) {
    const int cur = t & 1;          // compile-time under full unroll

    // (1) issue loads for tile t+2 into pf[cur] (freed last iteration)
    if (t + 2 < NT) {
      const float* src = stage_src + (t + 2) * SBLK + sl;
      #pragma unroll
      for (int e = 0; e < 8; ++e) pf[cur][e] = src[(size_t)e * NS];
    }
    // (2) pack + write tile t+1 (arrived ~1 full tile ago; counted vmcnt)
    //     into sT[cur^1], which all waves finished reading at tile t-1.
    if (t + 1 < NT)
      *reinterpret_cast<i32x4*>(sT[cur ^ 1] + byt) = pack8(pf[cur ^ 1]);

    // (3) compute tile t from sT[cur]: nf in pairs for v_max3 fusion
    #pragma unroll
    for (int nfp = 0; nfp < 2; ++nfp) {
      const int scol0 = nfp * 32 + (lane & 15);
      bf16x8 bfr0[2], bfr1[2];
      #pragma unroll
      for (int ks = 0; ks < 2; ++ks) {
        const int slot = ((ks * 4 + (lane >> 4)) ^ (scol0 & 7)) << 4;
        bfr0[ks] = *reinterpret_cast<const bf16x8*>(sT[cur] + scol0 * 128 + slot);
        bfr1[ks] = *reinterpret_cast<const bf16x8*>(sT[cur] + (scol0 + 16) * 128 + slot);
      }
      #pragma unroll
      for (int mf = 0; mf < 4; ++mf) {
        const bf16x8 a0 = __builtin_bit_cast(bf16x8, afrag[mf][0]);
        const bf16x8 a1 = __builtin_bit_cast(bf16x8, afrag[mf][1]);
        f32x4 acc0 = __builtin_amdgcn_mfma_f32_16x16x32_bf16(a0, bfr0[0], kZero, 0, 0, 0);
        f32x4 acc1 = __builtin_amdgcn_mfma_f32_16x16x32_bf16(a0, bfr1[0], kZero, 0, 0, 0);
        acc0 = __builtin_amdgcn_mfma_f32_16x16x32_bf16(a1, bfr0[1], acc0, 0, 0, 0);
        acc1 = __builtin_amdgcn_mfma_f32_16x16x32_bf16(a1, bfr1[1], acc1, 0, 0, 0);
        #pragma unroll
        for (int j = 0; j < 4; ++j)
          rmax[mf][j] = fmaxf(rmax[mf][j], fmaxf(acc0[j], acc1[j]));  // v_max3
      }
    }

    // (4) one barrier per tile: publishes tile t+1's writes, and guarantees
    //     everyone is done reading sT[cur] before t+1 overwrites it.
    __syncthreads();
  }

  // ---- epilogue: max across the 16 col-lanes -> per-row max to ws ----
  float* rowp = part + (size_t)bid * QBLK + w * 64;
  #pragma unroll
  for (int mf = 0; mf < 4; ++mf) {
    #pragma unroll
    for (int j = 0; j < 4; ++j) {
      float v = rmax[mf][j];
      v = fmaxf(v, __shfl_xor(v, 1));
      v = fmaxf(v, __shfl_xor(v, 2));
      v = fmaxf(v, __shfl_xor(v, 4));
      v = fmaxf(v, __shfl_xor(v, 8));
      if ((lane & 15) == 0)
        rowp[mf * 16 + (lane >> 4) * 4 + j] = v;  // row-max for this q-row
    }
  }
}

// out[b] = mean_q max_ss rowmax -- 64 blocks x 256 threads, 8 q per thread
__global__ void bmd_reduce(const float* __restrict__ part, float* __restrict__ out) {
  const int b = blockIdx.x;
  const int tid = threadIdx.x;
  __shared__ float ws4[4];
  float sum = 0.f;
  #pragma unroll
  for (int k = 0; k < NQ / 256; ++k) {
    const int q = k * 256 + tid;
    const int qb = q >> 9;          // q / QBLK
    const int row = q & (QBLK - 1);
    float m = -INFINITY;
    #pragma unroll
    for (int ssi = 0; ssi < NSPLIT; ++ssi)
      m = fmaxf(m, part[((size_t)((ssi * QPB + qb) * NB + b)) * QBLK + row]);
    sum += m;
  }
  #pragma unroll
  for (int o = 1; o < 64; o <<= 1) sum += __shfl_xor(sum, o);
  if ((tid & 63) == 0) ws4[tid >> 6] = sum;
  __syncthreads();
  if (tid == 0) out[b] = (ws4[0] + ws4[1] + ws4[2] + ws4[3]) * (1.0f / NQ);
}

extern "C" void kernel_launch(void* const* d_in, const int* in_sizes, int n_in,
                              void* d_out, int out_size, void* d_ws, size_t ws_size,
                              hipStream_t stream) {
  const float* Q = (const float*)d_in[0];
  const float* S = (const float*)d_in[1];
  float* out = (float*)d_out;
  float* part = (float*)d_ws;  // NB*QPB*NSPLIT*QBLK = 256K floats = 1 MB
  bmd_main<<<dim3(NB * QPB * NSPLIT), dim3(512), 0, stream>>>(Q, S, part);
  bmd_reduce<<<dim3(NB), dim3(256), 0, stream>>>(part, out);
}

// Round 8
// 50.849 us; speedup vs baseline: 5.2279x; 5.2279x over previous
//
#include <hip/hip_runtime.h>
#include <hip/hip_bf16.h>

#define NB 64
#define ND 64
#define NQ 2048
#define NS 2048
#define QBLK 512           // q-rows per block (8 waves x 64)
#define SBLK 64
#define QPB 4              // q-blocks per batch = NQ/QBLK
#define NSPLIT 2           // s-range splits per (b,qb)
#define NSS (NS / NSPLIT)  // 1024 s-cols per block
#define NT (NSS / SBLK)    // 16 tiles per block

typedef float f32x4 __attribute__((ext_vector_type(4)));
typedef short bf16x8 __attribute__((ext_vector_type(8)));
typedef int i32x4 __attribute__((ext_vector_type(4)));

// f32 -> bf16 via compiler-visible packed convert (m240: beats inline asm).
__device__ inline i32x4 pack8(const float* f) {
  union { __hip_bfloat162 h2[4]; i32x4 v; } u;
  #pragma unroll
  for (int p = 0; p < 4; ++p)
    u.h2[p] = __float22bfloat162_rn(float2{f[2 * p], f[2 * p + 1]});
  return u.v;
}

// bid = ss*256 + qb*64 + b (b in low bits -> all blocks of batch b on XCD b%8)
// Block: batch b, 512 q-rows (8 waves x 64), s-cols [ss*1024, +1024).
// Depth-2 register prefetch with NAMED buffers fA/fB in a hand-written
// 2-tile loop body (rule #20: no runtime-indexed arrays -> no scratch).
// Load->use distance = one full compute phase + barrier (~700 cyc) covers
// HBM latency. One barrier per tile. S staged bf16 [s][d], 16B-slot XOR swz.
__global__ __launch_bounds__(512, 4) void bmd_main(
    const float* __restrict__ Q, const float* __restrict__ S,
    float* __restrict__ part) {
  const int bid = blockIdx.x;
  const int b  = bid & (NB - 1);
  const int qb = (bid >> 6) & (QPB - 1);
  const int ss = bid >> 8;
  const int q0 = qb * QBLK;
  const int sbase = ss * NSS;
  const int tid = threadIdx.x;
  const int lane = tid & 63;
  const int w = tid >> 6;   // 0..7

  __shared__ char sT[2][SBLK * 128];

  const float* Qb = Q + (size_t)b * ND * NQ;
  const float* Sb = S + (size_t)b * ND * NS;

  // staging: thread -> (d-octet dbq, s-col sl); 512 threads = 64s x 8 octets
  const int dbq = (tid >> 3) & 7;
  const int sl = (tid & 7) + ((tid >> 6) << 3);   // 0..63
  const int byt = sl * 128 + ((dbq ^ (sl & 7)) << 4);
  const float* stage_src = Sb + (size_t)dbq * 8 * NS + sbase;

  // ---- issue tile-0 / tile-1 loads first (hide under Q gather) ----
  float fA[8], fB[8];
  {
    const float* s0 = stage_src + sl;
    #pragma unroll
    for (int e = 0; e < 8; ++e) fA[e] = s0[(size_t)e * NS];
    const float* s1 = stage_src + SBLK + sl;
    #pragma unroll
    for (int e = 0; e < 8; ++e) fB[e] = s1[(size_t)e * NS];
  }

  // ---- A fragments: row = lane&15 (q), k = (lane>>4)*8+e (d) ----
  i32x4 afrag[4][2];  // [mf: 16 q-rows each][ks: k-step of 32]
  {
    const int qrow = q0 + w * 64 + (lane & 15);
    const int dbase = (lane >> 4) * 8;
    for (int mf = 0; mf < 4; ++mf)
      for (int ks = 0; ks < 2; ++ks) {
        const int d0 = ks * 32 + dbase;
        float f[8];
        #pragma unroll
        for (int e = 0; e < 8; ++e)
          f[e] = Qb[(size_t)(d0 + e) * NQ + (qrow + mf * 16)];
        afrag[mf][ks] = pack8(f);
      }
  }

  const f32x4 kZero = {0.f, 0.f, 0.f, 0.f};
  f32x4 rmax[4];
  #pragma unroll
  for (int mf = 0; mf < 4; ++mf)
    rmax[mf] = f32x4{-INFINITY, -INFINITY, -INFINITY, -INFINITY};

  // compute one 64q x 64s tile from LDS buffer `buf`
#define COMPUTE(buf)                                                          \
  {                                                                           \
    __builtin_amdgcn_s_setprio(1);                                            \
    _Pragma("unroll")                                                         \
    for (int nfp = 0; nfp < 2; ++nfp) {                                       \
      const int scol0 = nfp * 32 + (lane & 15);                               \
      bf16x8 bfr0[2], bfr1[2];                                                \
      _Pragma("unroll")                                                       \
      for (int ks = 0; ks < 2; ++ks) {                                        \
        const int slot = ((ks * 4 + (lane >> 4)) ^ (scol0 & 7)) << 4;         \
        bfr0[ks] = *reinterpret_cast<const bf16x8*>((buf) + scol0 * 128 + slot);        \
        bfr1[ks] = *reinterpret_cast<const bf16x8*>((buf) + (scol0 + 16) * 128 + slot); \
      }                                                                       \
      _Pragma("unroll")                                                       \
      for (int mf = 0; mf < 4; ++mf) {                                        \
        const bf16x8 a0 = __builtin_bit_cast(bf16x8, afrag[mf][0]);           \
        const bf16x8 a1 = __builtin_bit_cast(bf16x8, afrag[mf][1]);           \
        f32x4 acc0 = __builtin_amdgcn_mfma_f32_16x16x32_bf16(a0, bfr0[0], kZero, 0, 0, 0); \
        f32x4 acc1 = __builtin_amdgcn_mfma_f32_16x16x32_bf16(a0, bfr1[0], kZero, 0, 0, 0); \
        acc0 = __builtin_amdgcn_mfma_f32_16x16x32_bf16(a1, bfr0[1], acc0, 0, 0, 0);        \
        acc1 = __builtin_amdgcn_mfma_f32_16x16x32_bf16(a1, bfr1[1], acc1, 0, 0, 0);        \
        _Pragma("unroll")                                                     \
        for (int j = 0; j < 4; ++j)                                           \
          rmax[mf][j] = fmaxf(rmax[mf][j], fmaxf(acc0[j], acc1[j]));          \
      }                                                                       \
    }                                                                         \
    __builtin_amdgcn_s_setprio(0);                                            \
  }

  // ---- stage tile 0, enter the pipeline ----
  *reinterpret_cast<i32x4*>(sT[0] + byt) = pack8(fA);
  __syncthreads();

  for (int i = 0; i < NT / 2; ++i) {
    const int t = 2 * i;
    // (1) issue loads for tile t+2 -> fA (fA's old data already in sT[0])
    if (t + 2 < NT) {
      const float* src = stage_src + (t + 2) * SBLK + sl;
      #pragma unroll
      for (int e = 0; e < 8; ++e) fA[e] = src[(size_t)e * NS];
    }
    // (2) pack tile t+1 (fB, in flight ~1 tile) -> sT[1]
    *reinterpret_cast<i32x4*>(sT[1] + byt) = pack8(fB);
    // (3) compute tile t from sT[0]
    COMPUTE(sT[0]);
    // (4) publish sT[1]; all reads of sT[0] done
    __syncthreads();
    // (5) issue loads for tile t+3 -> fB
    if (t + 3 < NT) {
      const float* src = stage_src + (t + 3) * SBLK + sl;
      #pragma unroll
      for (int e = 0; e < 8; ++e) fB[e] = src[(size_t)e * NS];
    }
    // (6) pack tile t+2 (fA) -> sT[0]
    if (t + 2 < NT)
      *reinterpret_cast<i32x4*>(sT[0] + byt) = pack8(fA);
    // (7) compute tile t+1 from sT[1]
    COMPUTE(sT[1]);
    // (8) publish sT[0]; all reads of sT[1] done
    __syncthreads();
  }
#undef COMPUTE

  // ---- epilogue: max across the 16 col-lanes -> per-row max to ws ----
  float* rowp = part + (size_t)bid * QBLK + w * 64;
  #pragma unroll
  for (int mf = 0; mf < 4; ++mf) {
    #pragma unroll
    for (int j = 0; j < 4; ++j) {
      float v = rmax[mf][j];
      v = fmaxf(v, __shfl_xor(v, 1));
      v = fmaxf(v, __shfl_xor(v, 2));
      v = fmaxf(v, __shfl_xor(v, 4));
      v = fmaxf(v, __shfl_xor(v, 8));
      if ((lane & 15) == 0)
        rowp[mf * 16 + (lane >> 4) * 4 + j] = v;  // row-max for this q-row
    }
  }
}

// out[b] = mean_q max_ss rowmax -- 64 blocks x 256 threads, 8 q per thread
__global__ void bmd_reduce(const float* __restrict__ part, float* __restrict__ out) {
  const int b = blockIdx.x;
  const int tid = threadIdx.x;
  __shared__ float ws4[4];
  float sum = 0.f;
  #pragma unroll
  for (int k = 0; k < NQ / 256; ++k) {
    const int q = k * 256 + tid;
    const int qb = q >> 9;          // q / QBLK
    const int row = q & (QBLK - 1);
    float m = -INFINITY;
    #pragma unroll
    for (int ssi = 0; ssi < NSPLIT; ++ssi)
      m = fmaxf(m, part[((size_t)((ssi * QPB + qb) * NB + b)) * QBLK + row]);
    sum += m;
  }
  #pragma unroll
  for (int o = 1; o < 64; o <<= 1) sum += __shfl_xor(sum, o);
  if ((tid & 63) == 0) ws4[tid >> 6] = sum;
  __syncthreads();
  if (tid == 0) out[b] = (ws4[0] + ws4[1] + ws4[2] + ws4[3]) * (1.0f / NQ);
}

extern "C" void kernel_launch(void* const* d_in, const int* in_sizes, int n_in,
                              void* d_out, int out_size, void* d_ws, size_t ws_size,
                              hipStream_t stream) {
  const float* Q = (const float*)d_in[0];
  const float* S = (const float*)d_in[1];
  float* out = (float*)d_out;
  float* part = (float*)d_ws;  // NB*QPB*NSPLIT*QBLK = 256K floats = 1 MB
  bmd_main<<<dim3(NB * QPB * NSPLIT), dim3(512), 0, stream>>>(Q, S, part);
  bmd_reduce<<<dim3(NB), dim3(256), 0, stream>>>(part, out);
}